// Round 1
// baseline (321.810 us; speedup 1.0000x reference)
//
#include <hip/hip_runtime.h>
#include <hip/hip_bf16.h>

#define NT 64
#define DIM 128
#define NH 4
#define HD 32

typedef __attribute__((ext_vector_type(8))) short short8;
typedef __attribute__((ext_vector_type(4))) short short4v;
typedef __attribute__((ext_vector_type(8))) __bf16 bf16x8;
typedef __attribute__((ext_vector_type(4))) float floatx4;

__device__ __forceinline__ short f2bf(float f) {
  unsigned u = __builtin_bit_cast(unsigned, f);
  u += 0x7FFFu + ((u >> 16) & 1u);
  return (short)(u >> 16);
}

__device__ __forceinline__ bf16x8 ldsfrag(const short* p) {
  return __builtin_bit_cast(bf16x8, *(const short8*)p);
}

// load 8 consecutive f32 weights, convert to bf16 fragment
__device__ __forceinline__ bf16x8 wfrag(const float* p) {
  float4 a = *(const float4*)p;
  float4 b = *(const float4*)(p + 4);
  short8 v;
  v[0]=f2bf(a.x); v[1]=f2bf(a.y); v[2]=f2bf(a.z); v[3]=f2bf(a.w);
  v[4]=f2bf(b.x); v[5]=f2bf(b.y); v[6]=f2bf(b.z); v[7]=f2bf(b.w);
  return __builtin_bit_cast(bf16x8, v);
}

#define MFMA(a,b,c) __builtin_amdgcn_mfma_f32_16x16x32_bf16(a,b,c,0,0,0)

// stage a 64x128 f32 tile -> LDS bf16 [64][136]
__device__ __forceinline__ void stage_tile(const float* __restrict__ src, short* dst_base, int tid) {
  int r = tid >> 2, c0 = (tid & 3) * 32;
  const float4* s = (const float4*)(src + r * DIM + c0);
  short* dst = dst_base + r * 136 + c0;
#pragma unroll
  for (int i = 0; i < 4; ++i) {
    float4 a = s[2*i], b = s[2*i+1];
    short8 v;
    v[0]=f2bf(a.x); v[1]=f2bf(a.y); v[2]=f2bf(a.z); v[3]=f2bf(a.w);
    v[4]=f2bf(b.x); v[5]=f2bf(b.y); v[6]=f2bf(b.z); v[7]=f2bf(b.w);
    *(short8*)(dst + i*8) = v;
  }
}

// ---------------- pre-kernel: CPB MLP + bias packing ----------------
// bias_packed[f], f = (((h*4+mt)*4+nt)*64+lane)*4+i  (MFMA C-fragment order)
__global__ void cpb_bias_kernel(const float* __restrict__ table,
                                const float* __restrict__ w1,
                                const float* __restrict__ b1,
                                const float* __restrict__ w2,
                                const int*   __restrict__ idx,
                                float* __restrict__ bias_packed) {
  __shared__ float logits[225][4];
  int t = threadIdx.x;
  if (t < 225) {
    float t0 = table[2*t], t1 = table[2*t+1];
    float a0=0.f, a1=0.f, a2=0.f, a3=0.f;
    for (int j = 0; j < 512; ++j) {
      float h = fmaxf(0.f, t0 * w1[2*j] + t1 * w1[2*j+1] + b1[j]);
      a0 += h * w2[j];
      a1 += h * w2[512 + j];
      a2 += h * w2[1024 + j];
      a3 += h * w2[1536 + j];
    }
    logits[t][0]=a0; logits[t][1]=a1; logits[t][2]=a2; logits[t][3]=a3;
  }
  __syncthreads();
  for (int f = t; f < 16384; f += 256) {
    int i    = f & 3;
    int lane = (f >> 2) & 63;
    int nt   = (f >> 8) & 3;
    int mt   = (f >> 10) & 3;
    int h    = (f >> 12) & 3;
    int r = mt*16 + (lane >> 4)*4 + i;
    int c = nt*16 + (lane & 15);
    int p = idx[r*64 + c];
    float v = logits[p][h];
    bias_packed[f] = 16.f / (1.f + __expf(-v));
  }
}

// ---------------- main fused kernel: one block per window ----------------
__global__ __launch_bounds__(256, 2)
void swin_ctx_attn_kernel(const float* __restrict__ x, const float* __restrict__ ctx,
                          const float* __restrict__ mask,
                          const float* __restrict__ q_w, const float* __restrict__ q_b,
                          const float* __restrict__ kv_w, const float* __restrict__ v_b,
                          const float* __restrict__ logit_scale,
                          const float* __restrict__ proj_w, const float* __restrict__ proj_b,
                          const float* __restrict__ bias_p,
                          float* __restrict__ out) {
  __shared__ short lds[38400] __attribute__((aligned(16)));
  const int tid  = threadIdx.x;
  const int lane = tid & 63;
  const int w    = tid >> 6;      // wave == head
  const int b    = blockIdx.x;
  const int lr   = lane & 15;     // A row-in-tile / B,C column
  const int lg   = lane >> 4;     // k-group / C row-group

  short* stage = lds;                         // [64][136] : x -> ctx -> out_pre
  short* hb    = lds + 8704 + w * 7424;       // per-head private region
  short* qn    = hb;                          // [64][40]
  short* kn    = hb + 2560;                   // [64][40]
  short* attnb = hb;                          // [64][72], overlays qn+kn
  short* vT    = hb + 5120;                   // [32][72]  (vT[c][token])

  // ---- stage x ----
  stage_tile(x + (size_t)b * (NT*DIM), stage, tid);
  __syncthreads();

  // ---- Q = x @ q_w.T + q_b ; l2norm per head-row ; -> qn ----
  {
    floatx4 acc[4][2] = {};
    for (int ks = 0; ks < 4; ++ks) {
      bf16x8 A[4];
#pragma unroll
      for (int mt = 0; mt < 4; ++mt)
        A[mt] = ldsfrag(stage + (mt*16 + lr)*136 + ks*32 + lg*8);
#pragma unroll
      for (int nt = 0; nt < 2; ++nt) {
        bf16x8 B = wfrag(q_w + (size_t)(w*32 + nt*16 + lr)*DIM + ks*32 + lg*8);
#pragma unroll
        for (int mt = 0; mt < 4; ++mt)
          acc[mt][nt] = MFMA(A[mt], B, acc[mt][nt]);
      }
    }
    float qb0 = q_b[w*32 + lr], qb1 = q_b[w*32 + 16 + lr];
#pragma unroll
    for (int mt = 0; mt < 4; ++mt) {
      floatx4 ss;
#pragma unroll
      for (int i = 0; i < 4; ++i) {
        acc[mt][0][i] += qb0; acc[mt][1][i] += qb1;
        ss[i] = acc[mt][0][i]*acc[mt][0][i] + acc[mt][1][i]*acc[mt][1][i];
      }
      for (int m = 1; m < 16; m <<= 1)
#pragma unroll
        for (int i = 0; i < 4; ++i) ss[i] += __shfl_xor(ss[i], m, 64);
#pragma unroll
      for (int i = 0; i < 4; ++i) {
        float sc = 1.0f / fmaxf(sqrtf(ss[i]), 1e-12f);
        int row = mt*16 + lg*4 + i;
        qn[row*40 + lr]      = f2bf(acc[mt][0][i] * sc);
        qn[row*40 + 16 + lr] = f2bf(acc[mt][1][i] * sc);
      }
    }
  }
  __syncthreads();   // all waves done reading x from stage

  // ---- stage ctx (reuse stage) ----
  stage_tile(ctx + (size_t)b * (NT*DIM), stage, tid);
  __syncthreads();

  // ---- K = ctx @ kv_w[0:128].T ; l2norm ; -> kn ----
  {
    floatx4 acc[4][2] = {};
    for (int ks = 0; ks < 4; ++ks) {
      bf16x8 A[4];
#pragma unroll
      for (int mt = 0; mt < 4; ++mt)
        A[mt] = ldsfrag(stage + (mt*16 + lr)*136 + ks*32 + lg*8);
#pragma unroll
      for (int nt = 0; nt < 2; ++nt) {
        bf16x8 B = wfrag(kv_w + (size_t)(w*32 + nt*16 + lr)*DIM + ks*32 + lg*8);
#pragma unroll
        for (int mt = 0; mt < 4; ++mt)
          acc[mt][nt] = MFMA(A[mt], B, acc[mt][nt]);
      }
    }
#pragma unroll
    for (int mt = 0; mt < 4; ++mt) {
      floatx4 ss;
#pragma unroll
      for (int i = 0; i < 4; ++i)
        ss[i] = acc[mt][0][i]*acc[mt][0][i] + acc[mt][1][i]*acc[mt][1][i];
      for (int m = 1; m < 16; m <<= 1)
#pragma unroll
        for (int i = 0; i < 4; ++i) ss[i] += __shfl_xor(ss[i], m, 64);
#pragma unroll
      for (int i = 0; i < 4; ++i) {
        float sc = 1.0f / fmaxf(sqrtf(ss[i]), 1e-12f);
        int row = mt*16 + lg*4 + i;
        kn[row*40 + lr]      = f2bf(acc[mt][0][i] * sc);
        kn[row*40 + 16 + lr] = f2bf(acc[mt][1][i] * sc);
      }
    }
  }

  // ---- V = ctx @ kv_w[128:256].T + v_b ; -> vT (transposed) ----
  {
    floatx4 acc[4][2] = {};
    for (int ks = 0; ks < 4; ++ks) {
      bf16x8 A[4];
#pragma unroll
      for (int mt = 0; mt < 4; ++mt)
        A[mt] = ldsfrag(stage + (mt*16 + lr)*136 + ks*32 + lg*8);
#pragma unroll
      for (int nt = 0; nt < 2; ++nt) {
        bf16x8 B = wfrag(kv_w + (size_t)(DIM + w*32 + nt*16 + lr)*DIM + ks*32 + lg*8);
#pragma unroll
        for (int mt = 0; mt < 4; ++mt)
          acc[mt][nt] = MFMA(A[mt], B, acc[mt][nt]);
      }
    }
    float vb0 = v_b[w*32 + lr], vb1 = v_b[w*32 + 16 + lr];
#pragma unroll
    for (int mt = 0; mt < 4; ++mt)
#pragma unroll
      for (int nt = 0; nt < 2; ++nt) {
        float vb = nt ? vb1 : vb0;
        short4v s4;
#pragma unroll
        for (int i = 0; i < 4; ++i) s4[i] = f2bf(acc[mt][nt][i] + vb);
        *(short4v*)(vT + (nt*16 + lr)*72 + mt*16 + lg*4) = s4;
      }
  }
  // kn/vT/qn are wave-private; ensure this wave's LDS writes have landed
  asm volatile("s_waitcnt lgkmcnt(0)" ::: "memory");

  // ---- S = qn @ kn^T (64x64, K=32) ----
  floatx4 sacc[4][4] = {};
  {
    bf16x8 A[4];
#pragma unroll
    for (int mt = 0; mt < 4; ++mt)
      A[mt] = ldsfrag(qn + (mt*16 + lr)*40 + lg*8);
#pragma unroll
    for (int nt = 0; nt < 4; ++nt) {
      bf16x8 B = ldsfrag(kn + (nt*16 + lr)*40 + lg*8);
#pragma unroll
      for (int mt = 0; mt < 4; ++mt)
        sacc[mt][nt] = MFMA(A[mt], B, sacc[mt][nt]);
    }
  }

  // ---- scale, +bias, +mask, softmax ----
  {
    float scl = expf(fminf(logit_scale[w], 4.605170185988091f));  // log(100)
    int wimg = b & 63;
#pragma unroll
    for (int mt = 0; mt < 4; ++mt)
#pragma unroll
      for (int nt = 0; nt < 4; ++nt) {
        floatx4 bias4 = ((const floatx4*)bias_p)[(w*16 + mt*4 + nt)*64 + lane];
#pragma unroll
        for (int i = 0; i < 4; ++i) {
          int r = mt*16 + lg*4 + i, c = nt*16 + lr;
          sacc[mt][nt][i] = sacc[mt][nt][i]*scl + bias4[i] + mask[((size_t)wimg*64 + r)*64 + c];
        }
      }
#pragma unroll
    for (int mt = 0; mt < 4; ++mt) {
      floatx4 rmax;
#pragma unroll
      for (int i = 0; i < 4; ++i)
        rmax[i] = fmaxf(fmaxf(sacc[mt][0][i], sacc[mt][1][i]), fmaxf(sacc[mt][2][i], sacc[mt][3][i]));
      for (int m = 1; m < 16; m <<= 1)
#pragma unroll
        for (int i = 0; i < 4; ++i) rmax[i] = fmaxf(rmax[i], __shfl_xor(rmax[i], m, 64));
      floatx4 rsum = {};
#pragma unroll
      for (int nt = 0; nt < 4; ++nt)
#pragma unroll
        for (int i = 0; i < 4; ++i) {
          sacc[mt][nt][i] = __expf(sacc[mt][nt][i] - rmax[i]);
          rsum[i] += sacc[mt][nt][i];
        }
      for (int m = 1; m < 16; m <<= 1)
#pragma unroll
        for (int i = 0; i < 4; ++i) rsum[i] += __shfl_xor(rsum[i], m, 64);
#pragma unroll
      for (int i = 0; i < 4; ++i) rsum[i] = 1.0f / rsum[i];
#pragma unroll
      for (int nt = 0; nt < 4; ++nt)
#pragma unroll
        for (int i = 0; i < 4; ++i) sacc[mt][nt][i] *= rsum[i];
    }
  }

  // write P (bf16) over qn/kn region (wave-private)
#pragma unroll
  for (int mt = 0; mt < 4; ++mt)
#pragma unroll
    for (int nt = 0; nt < 4; ++nt)
#pragma unroll
      for (int i = 0; i < 4; ++i)
        attnb[(mt*16 + lg*4 + i)*72 + nt*16 + lr] = f2bf(sacc[mt][nt][i]);
  asm volatile("s_waitcnt lgkmcnt(0)" ::: "memory");

  // ---- O = P @ V (64x32, K=64) ----
  floatx4 oacc[4][2] = {};
  for (int ks = 0; ks < 2; ++ks) {
    bf16x8 A[4];
#pragma unroll
    for (int mt = 0; mt < 4; ++mt)
      A[mt] = ldsfrag(attnb + (mt*16 + lr)*72 + ks*32 + lg*8);
#pragma unroll
    for (int nt = 0; nt < 2; ++nt) {
      bf16x8 B = ldsfrag(vT + (nt*16 + lr)*72 + ks*32 + lg*8);
#pragma unroll
      for (int mt = 0; mt < 4; ++mt)
        oacc[mt][nt] = MFMA(A[mt], B, oacc[mt][nt]);
    }
  }

  __syncthreads();   // all waves done with ctx in stage
  // out_pre (bf16) -> stage
#pragma unroll
  for (int mt = 0; mt < 4; ++mt)
#pragma unroll
    for (int nt = 0; nt < 2; ++nt)
#pragma unroll
      for (int i = 0; i < 4; ++i)
        stage[(mt*16 + lg*4 + i)*136 + w*32 + nt*16 + lr] = f2bf(oacc[mt][nt][i]);
  __syncthreads();

  // ---- out = out_pre @ proj_w.T + proj_b ----
  {
    floatx4 acc[4][2] = {};
    for (int ks = 0; ks < 4; ++ks) {
      bf16x8 A[4];
#pragma unroll
      for (int mt = 0; mt < 4; ++mt)
        A[mt] = ldsfrag(stage + (mt*16 + lr)*136 + ks*32 + lg*8);
#pragma unroll
      for (int nt = 0; nt < 2; ++nt) {
        bf16x8 B = wfrag(proj_w + (size_t)(w*32 + nt*16 + lr)*DIM + ks*32 + lg*8);
#pragma unroll
        for (int mt = 0; mt < 4; ++mt)
          acc[mt][nt] = MFMA(A[mt], B, acc[mt][nt]);
      }
    }
    float pb0 = proj_b[w*32 + lr], pb1 = proj_b[w*32 + 16 + lr];
    float* outp = out + (size_t)b * (NT*DIM);
#pragma unroll
    for (int mt = 0; mt < 4; ++mt)
#pragma unroll
      for (int nt = 0; nt < 2; ++nt) {
        float pb = nt ? pb1 : pb0;
#pragma unroll
        for (int i = 0; i < 4; ++i)
          outp[(mt*16 + lg*4 + i)*DIM + w*32 + nt*16 + lr] = acc[mt][nt][i] + pb;
      }
  }
}

extern "C" void kernel_launch(void* const* d_in, const int* in_sizes, int n_in,
                              void* d_out, int out_size, void* d_ws, size_t ws_size,
                              hipStream_t stream) {
  const float* x     = (const float*)d_in[0];
  const float* ctx   = (const float*)d_in[1];
  const float* mask  = (const float*)d_in[2];
  const float* q_w   = (const float*)d_in[3];
  const float* q_b   = (const float*)d_in[4];
  const float* kv_w  = (const float*)d_in[5];
  const float* v_b   = (const float*)d_in[6];
  const float* ls    = (const float*)d_in[7];
  const float* w1    = (const float*)d_in[8];
  const float* b1    = (const float*)d_in[9];
  const float* w2    = (const float*)d_in[10];
  const float* pw    = (const float*)d_in[11];
  const float* pb    = (const float*)d_in[12];
  const float* table = (const float*)d_in[13];
  const int*   idx   = (const int*)d_in[14];

  float* bias_p = (float*)d_ws;   // 16384 floats = 64 KB
  int B = in_sizes[0] / (NT * DIM);

  cpb_bias_kernel<<<1, 256, 0, stream>>>(table, w1, b1, w2, idx, bias_p);
  swin_ctx_attn_kernel<<<B, 256, 0, stream>>>(x, ctx, mask, q_w, q_b, kv_w, v_b,
                                              ls, pw, pb, bias_p, (float*)d_out);
}

// Round 2
// 273.116 us; speedup vs baseline: 1.1783x; 1.1783x over previous
//
#include <hip/hip_runtime.h>
#include <hip/hip_bf16.h>

#define NT 64
#define DIM 128
#define NH 4
#define HD 32

typedef __attribute__((ext_vector_type(8))) short short8;
typedef __attribute__((ext_vector_type(4))) short short4v;
typedef __attribute__((ext_vector_type(8))) __bf16 bf16x8;
typedef __attribute__((ext_vector_type(4))) float floatx4;

__device__ __forceinline__ short f2bf(float f) {
  unsigned u = __builtin_bit_cast(unsigned, f);
  u += 0x7FFFu + ((u >> 16) & 1u);
  return (short)(u >> 16);
}

__device__ __forceinline__ bf16x8 ldsfrag(const short* p) {
  return __builtin_bit_cast(bf16x8, *(const short8*)p);
}

#define MFMA(a,b,c) __builtin_amdgcn_mfma_f32_16x16x32_bf16(a,b,c,0,0,0)

// ---------------- pre-kernel: CPB MLP + bias packing + weight bf16 pack ----
// block 0: bias_packed[f], f = (((h*4+mt)*4+nt)*64+lane)*4+i  (MFMA C order)
// blocks 1..16: convert [q_w | kv_w | proj_w] (65536 f32) -> bf16
__global__ void prep_kernel(const float* __restrict__ table,
                            const float* __restrict__ w1,
                            const float* __restrict__ b1,
                            const float* __restrict__ w2,
                            const int*   __restrict__ idx,
                            const float* __restrict__ q_w,
                            const float* __restrict__ kv_w,
                            const float* __restrict__ proj_w,
                            float* __restrict__ bias_packed,
                            short* __restrict__ wbf) {
  int t = threadIdx.x;
  if (blockIdx.x == 0) {
    __shared__ float logits[225][4];
    if (t < 225) {
      float t0 = table[2*t], t1 = table[2*t+1];
      float a0=0.f, a1=0.f, a2=0.f, a3=0.f;
      for (int j = 0; j < 512; ++j) {
        float h = fmaxf(0.f, t0 * w1[2*j] + t1 * w1[2*j+1] + b1[j]);
        a0 += h * w2[j];
        a1 += h * w2[512 + j];
        a2 += h * w2[1024 + j];
        a3 += h * w2[1536 + j];
      }
      logits[t][0]=a0; logits[t][1]=a1; logits[t][2]=a2; logits[t][3]=a3;
    }
    __syncthreads();
    for (int f = t; f < 16384; f += 256) {
      int i    = f & 3;
      int lane = (f >> 2) & 63;
      int nt   = (f >> 8) & 3;
      int mt   = (f >> 10) & 3;
      int h    = (f >> 12) & 3;
      int r = mt*16 + (lane >> 4)*4 + i;
      int c = nt*16 + (lane & 15);
      int p = idx[r*64 + c];
      float v = logits[p][h];
      bias_packed[f] = 16.f / (1.f + __expf(-v));
    }
  } else {
    int gidx = (blockIdx.x - 1) * 4096 + t * 16;
    const float* src; int off;
    if (gidx < 16384)      { src = q_w;    off = gidx; }
    else if (gidx < 49152) { src = kv_w;   off = gidx - 16384; }
    else                   { src = proj_w; off = gidx - 49152; }
    const float4* s = (const float4*)(src + off);
    short* dst = wbf + gidx;
#pragma unroll
    for (int i = 0; i < 2; ++i) {
      float4 a = s[2*i], b = s[2*i+1];
      short8 v;
      v[0]=f2bf(a.x); v[1]=f2bf(a.y); v[2]=f2bf(a.z); v[3]=f2bf(a.w);
      v[4]=f2bf(b.x); v[5]=f2bf(b.y); v[6]=f2bf(b.z); v[7]=f2bf(b.w);
      *(short8*)(dst + i*8) = v;
    }
  }
}

// ---------------- main fused kernel: one block (512 thr) per window --------
// wave = (head h, row-half s): handles token rows s*32..s*32+32, channels h*32..+32
__global__ __launch_bounds__(512, 4)
void swin_ctx_attn_kernel(const float* __restrict__ x, const float* __restrict__ ctx,
                          const float* __restrict__ mask,
                          const short* __restrict__ wq, const float* __restrict__ q_b,
                          const short* __restrict__ wkv, const float* __restrict__ v_b,
                          const float* __restrict__ logit_scale,
                          const short* __restrict__ wproj, const float* __restrict__ proj_b,
                          const float* __restrict__ bias_p,
                          float* __restrict__ out) {
  __shared__ short lds[38400] __attribute__((aligned(16)));
  const int tid  = threadIdx.x;
  const int lane = tid & 63;
  const int wv   = tid >> 6;      // 0..7
  const int h    = wv >> 1;       // head
  const int s    = wv & 1;        // row-half
  const int b    = blockIdx.x;
  const int lr   = lane & 15;     // A row-in-tile / B,C column
  const int lg   = lane >> 4;     // k-group / C row-group

  short* stage = lds;                         // [64][136] : x -> ctx -> out_pre
  short* hb    = lds + 8704 + h * 7424;       // per-head region
  short* qn    = hb;                          // [64][40]
  short* kn    = hb + 2560;                   // [64][40]
  short* attnb = hb;                          // [64][72], overlays qn+kn
  short* vT    = hb + 5120;                   // [32][72]  (vT[ch][token])

  // ---- stage x (each thread: 16 floats) ----
  const int sr = tid >> 3, sc = (tid & 7) * 16;
  {
    const float4* sx = (const float4*)(x + (size_t)b * (NT*DIM) + sr*DIM + sc);
    short* d = stage + sr*136 + sc;
#pragma unroll
    for (int i = 0; i < 2; ++i) {
      float4 a = sx[2*i], bb = sx[2*i+1];
      short8 v;
      v[0]=f2bf(a.x); v[1]=f2bf(a.y); v[2]=f2bf(a.z); v[3]=f2bf(a.w);
      v[4]=f2bf(bb.x); v[5]=f2bf(bb.y); v[6]=f2bf(bb.z); v[7]=f2bf(bb.w);
      *(short8*)(d + i*8) = v;
    }
  }
  // ---- prefetch ctx into registers (hides HBM latency under Q GEMM) ----
  float4 cr[4];
  {
    const float4* cs = (const float4*)(ctx + (size_t)b * (NT*DIM) + sr*DIM + sc);
#pragma unroll
    for (int i = 0; i < 4; ++i) cr[i] = cs[i];
  }
  __syncthreads();  // B1: x staged

  // ---- Q = x @ q_w.T + q_b ; l2norm ; -> qn (rows s*32..+32) ----
  {
    floatx4 acc[2][2] = {};
    for (int ks = 0; ks < 4; ++ks) {
      bf16x8 A[2];
#pragma unroll
      for (int m = 0; m < 2; ++m)
        A[m] = ldsfrag(stage + (s*32 + m*16 + lr)*136 + ks*32 + lg*8);
#pragma unroll
      for (int nt = 0; nt < 2; ++nt) {
        bf16x8 B = ldsfrag(wq + (h*32 + nt*16 + lr)*DIM + ks*32 + lg*8);
#pragma unroll
        for (int m = 0; m < 2; ++m)
          acc[m][nt] = MFMA(A[m], B, acc[m][nt]);
      }
    }
    float qb0 = q_b[h*32 + lr], qb1 = q_b[h*32 + 16 + lr];
#pragma unroll
    for (int m = 0; m < 2; ++m) {
      floatx4 ss;
#pragma unroll
      for (int i = 0; i < 4; ++i) {
        acc[m][0][i] += qb0; acc[m][1][i] += qb1;
        ss[i] = acc[m][0][i]*acc[m][0][i] + acc[m][1][i]*acc[m][1][i];
      }
      for (int mm = 1; mm < 16; mm <<= 1)
#pragma unroll
        for (int i = 0; i < 4; ++i) ss[i] += __shfl_xor(ss[i], mm, 64);
#pragma unroll
      for (int i = 0; i < 4; ++i) {
        float sc2 = 1.0f / fmaxf(sqrtf(ss[i]), 1e-12f);
        int row = s*32 + m*16 + lg*4 + i;
        qn[row*40 + lr]      = f2bf(acc[m][0][i] * sc2);
        qn[row*40 + 16 + lr] = f2bf(acc[m][1][i] * sc2);
      }
    }
  }
  __syncthreads();  // B2: all stage-x reads done

  // ---- write prefetched ctx -> stage ----
  {
    short* d = stage + sr*136 + sc;
#pragma unroll
    for (int i = 0; i < 2; ++i) {
      float4 a = cr[2*i], bb = cr[2*i+1];
      short8 v;
      v[0]=f2bf(a.x); v[1]=f2bf(a.y); v[2]=f2bf(a.z); v[3]=f2bf(a.w);
      v[4]=f2bf(bb.x); v[5]=f2bf(bb.y); v[6]=f2bf(bb.z); v[7]=f2bf(bb.w);
      *(short8*)(d + i*8) = v;
    }
  }
  __syncthreads();  // B3: ctx staged

  // ---- K = ctx @ kv_w[0:128].T ; l2norm ; -> kn (rows s*32..+32) ----
  {
    floatx4 acc[2][2] = {};
    for (int ks = 0; ks < 4; ++ks) {
      bf16x8 A[2];
#pragma unroll
      for (int m = 0; m < 2; ++m)
        A[m] = ldsfrag(stage + (s*32 + m*16 + lr)*136 + ks*32 + lg*8);
#pragma unroll
      for (int nt = 0; nt < 2; ++nt) {
        bf16x8 B = ldsfrag(wkv + (h*32 + nt*16 + lr)*DIM + ks*32 + lg*8);
#pragma unroll
        for (int m = 0; m < 2; ++m)
          acc[m][nt] = MFMA(A[m], B, acc[m][nt]);
      }
    }
#pragma unroll
    for (int m = 0; m < 2; ++m) {
      floatx4 ss;
#pragma unroll
      for (int i = 0; i < 4; ++i)
        ss[i] = acc[m][0][i]*acc[m][0][i] + acc[m][1][i]*acc[m][1][i];
      for (int mm = 1; mm < 16; mm <<= 1)
#pragma unroll
        for (int i = 0; i < 4; ++i) ss[i] += __shfl_xor(ss[i], mm, 64);
#pragma unroll
      for (int i = 0; i < 4; ++i) {
        float sc2 = 1.0f / fmaxf(sqrtf(ss[i]), 1e-12f);
        int row = s*32 + m*16 + lg*4 + i;
        kn[row*40 + lr]      = f2bf(acc[m][0][i] * sc2);
        kn[row*40 + 16 + lr] = f2bf(acc[m][1][i] * sc2);
      }
    }
  }

  // ---- V = ctx @ kv_w[128:256].T + v_b ; -> vT (cols s*32..+32) ----
  {
    floatx4 acc[2][2] = {};
    for (int ks = 0; ks < 4; ++ks) {
      bf16x8 A[2];
#pragma unroll
      for (int m = 0; m < 2; ++m)
        A[m] = ldsfrag(stage + (s*32 + m*16 + lr)*136 + ks*32 + lg*8);
#pragma unroll
      for (int nt = 0; nt < 2; ++nt) {
        bf16x8 B = ldsfrag(wkv + (DIM + h*32 + nt*16 + lr)*DIM + ks*32 + lg*8);
#pragma unroll
        for (int m = 0; m < 2; ++m)
          acc[m][nt] = MFMA(A[m], B, acc[m][nt]);
      }
    }
    float vb0 = v_b[h*32 + lr], vb1 = v_b[h*32 + 16 + lr];
#pragma unroll
    for (int m = 0; m < 2; ++m)
#pragma unroll
      for (int nt = 0; nt < 2; ++nt) {
        float vb = nt ? vb1 : vb0;
        short4v s4;
#pragma unroll
        for (int i = 0; i < 4; ++i) s4[i] = f2bf(acc[m][nt][i] + vb);
        *(short4v*)(vT + (nt*16 + lr)*72 + s*32 + m*16 + lg*4) = s4;
      }
  }
  __syncthreads();  // B4: kn + vT complete

  // ---- S = qn @ kn^T (rows s*32..+32 x 64, K=32) ----
  floatx4 sacc[2][4] = {};
  {
    bf16x8 A[2];
#pragma unroll
    for (int m = 0; m < 2; ++m)
      A[m] = ldsfrag(qn + (s*32 + m*16 + lr)*40 + lg*8);
#pragma unroll
    for (int nt = 0; nt < 4; ++nt) {
      bf16x8 B = ldsfrag(kn + (nt*16 + lr)*40 + lg*8);
#pragma unroll
      for (int m = 0; m < 2; ++m)
        sacc[m][nt] = MFMA(A[m], B, sacc[m][nt]);
    }
  }
  __syncthreads();  // B5: all qn/kn reads done (attnb may now overwrite)

  // ---- scale, +bias, +mask, softmax (own rows) ----
  {
    float scl = __expf(fminf(logit_scale[h], 4.605170185988091f));  // log(100)
    int wimg = b & 63;
#pragma unroll
    for (int m = 0; m < 2; ++m)
#pragma unroll
      for (int nt = 0; nt < 4; ++nt) {
        floatx4 bias4 = ((const floatx4*)bias_p)[(h*16 + (s*2+m)*4 + nt)*64 + lane];
#pragma unroll
        for (int i = 0; i < 4; ++i) {
          int r = s*32 + m*16 + lg*4 + i, c = nt*16 + lr;
          sacc[m][nt][i] = sacc[m][nt][i]*scl + bias4[i] + mask[((size_t)wimg*64 + r)*64 + c];
        }
      }
#pragma unroll
    for (int m = 0; m < 2; ++m) {
      floatx4 rmax;
#pragma unroll
      for (int i = 0; i < 4; ++i)
        rmax[i] = fmaxf(fmaxf(sacc[m][0][i], sacc[m][1][i]), fmaxf(sacc[m][2][i], sacc[m][3][i]));
      for (int mm = 1; mm < 16; mm <<= 1)
#pragma unroll
        for (int i = 0; i < 4; ++i) rmax[i] = fmaxf(rmax[i], __shfl_xor(rmax[i], mm, 64));
      floatx4 rsum = {};
#pragma unroll
      for (int nt = 0; nt < 4; ++nt)
#pragma unroll
        for (int i = 0; i < 4; ++i) {
          sacc[m][nt][i] = __expf(sacc[m][nt][i] - rmax[i]);
          rsum[i] += sacc[m][nt][i];
        }
      for (int mm = 1; mm < 16; mm <<= 1)
#pragma unroll
        for (int i = 0; i < 4; ++i) rsum[i] += __shfl_xor(rsum[i], mm, 64);
#pragma unroll
      for (int i = 0; i < 4; ++i) rsum[i] = 1.0f / rsum[i];
#pragma unroll
      for (int nt = 0; nt < 4; ++nt)
#pragma unroll
        for (int i = 0; i < 4; ++i) sacc[m][nt][i] *= rsum[i];
    }
  }

  // write P (bf16) to attnb own rows
#pragma unroll
  for (int m = 0; m < 2; ++m)
#pragma unroll
    for (int nt = 0; nt < 4; ++nt)
#pragma unroll
      for (int i = 0; i < 4; ++i)
        attnb[(s*32 + m*16 + lg*4 + i)*72 + nt*16 + lr] = f2bf(sacc[m][nt][i]);
  asm volatile("s_waitcnt lgkmcnt(0)" ::: "memory");

  // ---- O = P @ V (own 32 rows x 32 ch, K=64) ----
  floatx4 oacc[2][2] = {};
  for (int ks = 0; ks < 2; ++ks) {
    bf16x8 A[2];
#pragma unroll
    for (int m = 0; m < 2; ++m)
      A[m] = ldsfrag(attnb + (s*32 + m*16 + lr)*72 + ks*32 + lg*8);
#pragma unroll
    for (int nt = 0; nt < 2; ++nt) {
      bf16x8 B = ldsfrag(vT + (nt*16 + lr)*72 + ks*32 + lg*8);
#pragma unroll
      for (int m = 0; m < 2; ++m)
        oacc[m][nt] = MFMA(A[m], B, oacc[m][nt]);
    }
  }

  // out_pre (bf16) -> stage (stage-ctx reads all ended before B4)
#pragma unroll
  for (int m = 0; m < 2; ++m)
#pragma unroll
    for (int nt = 0; nt < 2; ++nt)
#pragma unroll
      for (int i = 0; i < 4; ++i)
        stage[(s*32 + m*16 + lg*4 + i)*136 + h*32 + nt*16 + lr] = f2bf(oacc[m][nt][i]);
  __syncthreads();  // B6: out_pre complete

  // ---- out = out_pre @ proj_w.T + proj_b ----
  {
    floatx4 acc[2][2] = {};
    for (int ks = 0; ks < 4; ++ks) {
      bf16x8 A[2];
#pragma unroll
      for (int m = 0; m < 2; ++m)
        A[m] = ldsfrag(stage + (s*32 + m*16 + lr)*136 + ks*32 + lg*8);
#pragma unroll
      for (int nt = 0; nt < 2; ++nt) {
        bf16x8 B = ldsfrag(wproj + (h*32 + nt*16 + lr)*DIM + ks*32 + lg*8);
#pragma unroll
        for (int m = 0; m < 2; ++m)
          acc[m][nt] = MFMA(A[m], B, acc[m][nt]);
      }
    }
    float pb0 = proj_b[h*32 + lr], pb1 = proj_b[h*32 + 16 + lr];
    float* outp = out + (size_t)b * (NT*DIM);
#pragma unroll
    for (int m = 0; m < 2; ++m)
#pragma unroll
      for (int nt = 0; nt < 2; ++nt) {
        float pb = nt ? pb1 : pb0;
#pragma unroll
        for (int i = 0; i < 4; ++i)
          outp[(s*32 + m*16 + lg*4 + i)*DIM + h*32 + nt*16 + lr] = acc[m][nt][i] + pb;
      }
  }
}

extern "C" void kernel_launch(void* const* d_in, const int* in_sizes, int n_in,
                              void* d_out, int out_size, void* d_ws, size_t ws_size,
                              hipStream_t stream) {
  const float* x     = (const float*)d_in[0];
  const float* ctx   = (const float*)d_in[1];
  const float* mask  = (const float*)d_in[2];
  const float* q_w   = (const float*)d_in[3];
  const float* q_b   = (const float*)d_in[4];
  const float* kv_w  = (const float*)d_in[5];
  const float* v_b   = (const float*)d_in[6];
  const float* ls    = (const float*)d_in[7];
  const float* w1    = (const float*)d_in[8];
  const float* b1    = (const float*)d_in[9];
  const float* w2    = (const float*)d_in[10];
  const float* pw    = (const float*)d_in[11];
  const float* pb    = (const float*)d_in[12];
  const float* table = (const float*)d_in[13];
  const int*   idx   = (const int*)d_in[14];

  float* bias_p = (float*)d_ws;                       // 16384 f32 = 64 KB
  short* wbf    = (short*)((char*)d_ws + 65536);      // 65536 bf16 = 128 KB
  short* wq     = wbf;
  short* wkv    = wbf + 16384;
  short* wproj  = wbf + 49152;
  int B = in_sizes[0] / (NT * DIM);

  prep_kernel<<<17, 256, 0, stream>>>(table, w1, b1, w2, idx, q_w, kv_w, pw,
                                      bias_p, wbf);
  swin_ctx_attn_kernel<<<B, 512, 0, stream>>>(x, ctx, mask, wq, q_b, wkv, v_b,
                                              ls, wproj, pb, bias_p, (float*)d_out);
}